// Round 1
// baseline (42408.948 us; speedup 1.0000x reference)
//
#include <hip/hip_runtime.h>
#include <hip/hip_cooperative_groups.h>

namespace cg = cooperative_groups;

#define BN 8
#define CN 128
#define HN 128
#define WN 256
#define PLANE (HN*WN)        // 32768
#define BSTRIDE (CN*PLANE)   // 4194304
#define WELEM (CN*CN*9)      // 147456 floats per direction

// Pack w[co][ci][k] -> Wp[co/NC][ci][k][NC] so a wave owning NC consecutive
// output channels reads NC*9 contiguous floats per ci at a wave-uniform
// address (scalar-cache path, s_load_dwordx16).
__global__ void pack_w_kernel(const float* __restrict__ w0, const float* __restrict__ w1,
                              const float* __restrict__ w2, const float* __restrict__ w3,
                              float* __restrict__ Wp) {
    int t = blockIdx.x * 256 + threadIdx.x;
    if (t >= 4 * WELEM) return;
    int p  = t / WELEM;
    int r  = t % WELEM;
    int co = r / (CN * 9);
    int q  = r % (CN * 9);
    int ci = q / 9;
    int k  = q % 9;
    const float* w = (p == 0) ? w0 : (p == 1) ? w1 : (p == 2) ? w2 : w3;
    int NC = (p < 2) ? 4 : 2;
    Wp[p * WELEM + (((co / NC) * CN + ci) * 9 + k) * NC + (co % NC)] = w[r];
}

// One pass of the recurrence, in place on T.
//   out[s] = x[s] + relu(conv1d(out[s_prev]))  along the line axis.
// NC      : output channels per wave (weights wave-uniform -> scalar loads)
// SSTRIDE : element stride along the scan axis
// LSTRIDE : element stride along the line (conv) axis
// SLEN    : scan length, LLEN : line length
template<int NC, int SSTRIDE, int LSTRIDE, int SLEN, int LLEN, bool REV>
__global__ void __launch_bounds__(256)
pass_kernel(float* __restrict__ T, const float* __restrict__ W3) {
    constexpr int NCOT = CN / (4 * NC);   // co tiles
    constexpr int NLT  = LLEN / 64;       // line tiles
    constexpr int LW   = 72;              // 64 + 8 halo
    __shared__ float sP[CN * LW];

    int blk  = blockIdx.x;
    int b    = blk / (NCOT * NLT);
    int rem  = blk % (NCOT * NLT);
    int cot  = rem / NLT;
    int lt   = rem % NLT;
    int b_off  = b * BSTRIDE;
    int l_base = lt * 64;
    int lane = threadIdx.x & 63;
    int wv   = __builtin_amdgcn_readfirstlane(threadIdx.x >> 6);
    int co0  = cot * (4 * NC) + wv * NC;
    const float* wg = W3 + (co0 / NC) * (CN * 9 * NC);  // wave-uniform

    cg::grid_group grid = cg::this_grid();

    for (int step = 1; step < SLEN; ++step) {
        int s  = REV ? (SLEN - 1 - step) : step;
        int sp = REV ? (s + 1) : (s - 1);

        // Stage previous (already-updated) line into LDS with zero-padded halo.
        const float* Tp = T + b_off + sp * SSTRIDE;
        for (int idx = threadIdx.x; idx < CN * LW; idx += 256) {
            int ci = idx / LW;
            int j  = idx % LW;
            int gl = l_base + j - 4;
            float v = 0.f;
            if (gl >= 0 && gl < LLEN) v = Tp[ci * PLANE + gl * LSTRIDE];
            sP[idx] = v;
        }
        __syncthreads();

        float acc[NC];
#pragma unroll
        for (int j = 0; j < NC; ++j) acc[j] = 0.f;

        for (int ci = 0; ci < CN; ++ci) {
            const float* wr = wg + ci * (9 * NC);   // NC*9 contiguous, uniform
            const float* pr = sP + ci * LW + lane;
#pragma unroll
            for (int k = 0; k < 9; ++k) {
                float pv = pr[k];
#pragma unroll
                for (int j = 0; j < NC; ++j) acc[j] += wr[k * NC + j] * pv;
            }
        }

        // out[s] = x[s] (current contents) + relu(acc)
#pragma unroll
        for (int j = 0; j < NC; ++j) {
            int oidx = b_off + (co0 + j) * PLANE + s * SSTRIDE + (l_base + lane) * LSTRIDE;
            float r = acc[j] > 0.f ? acc[j] : 0.f;
            T[oidx] += r;
        }
        grid.sync();
    }
}

extern "C" void kernel_launch(void* const* d_in, const int* in_sizes, int n_in,
                              void* d_out, int out_size, void* d_ws, size_t ws_size,
                              hipStream_t stream) {
    const float* x  = (const float*)d_in[0];
    const float* wd = (const float*)d_in[1];
    const float* wu = (const float*)d_in[2];
    const float* wr = (const float*)d_in[3];
    const float* wl = (const float*)d_in[4];
    float* T  = (float*)d_out;
    float* Wp = (float*)d_ws;   // 4 * 147456 floats = 2.36 MB

    // out starts as x; passes update it in place.
    hipMemcpyAsync(T, x, (size_t)BN * CN * HN * WN * sizeof(float),
                   hipMemcpyDeviceToDevice, stream);

    pack_w_kernel<<<(4 * WELEM + 255) / 256, 256, 0, stream>>>(wd, wu, wr, wl, Wp);

    float* W0 = Wp;
    float* W1 = Wp + WELEM;
    float* W2 = Wp + 2 * WELEM;
    float* W3p = Wp + 3 * WELEM;

    // Pass 0: down  (scan h fwd, line = w)
    {
        void* args[] = { &T, &W0 };
        hipLaunchCooperativeKernel((const void*)pass_kernel<4, WN, 1, HN, WN, false>,
                                   dim3(256), dim3(256), args, 0, stream);
    }
    // Pass 1: up    (scan h rev)
    {
        void* args[] = { &T, &W1 };
        hipLaunchCooperativeKernel((const void*)pass_kernel<4, WN, 1, HN, WN, true>,
                                   dim3(256), dim3(256), args, 0, stream);
    }
    // Pass 2: right (scan w fwd, line = h)
    {
        void* args[] = { &T, &W2 };
        hipLaunchCooperativeKernel((const void*)pass_kernel<2, 1, WN, WN, HN, false>,
                                   dim3(256), dim3(256), args, 0, stream);
    }
    // Pass 3: left  (scan w rev)
    {
        void* args[] = { &T, &W3p };
        hipLaunchCooperativeKernel((const void*)pass_kernel<2, 1, WN, WN, HN, true>,
                                   dim3(256), dim3(256), args, 0, stream);
    }
}

// Round 2
// 39797.052 us; speedup vs baseline: 1.0656x; 1.0656x over previous
//
#include <hip/hip_runtime.h>

#define BN 8
#define CN 128
#define HN 128
#define WN 256
#define PLANE (HN*WN)        // 32768
#define BSTRIDE (CN*PLANE)   // 4194304
#define WELEM (CN*CN*9)      // 147456 floats per direction

// Pack w[co][ci][k] -> Wp[co/2][ci][k][2]: a wave owning co-pair reads 18
// contiguous floats per ci at a wave-uniform address (scalar-cache path).
__global__ void pack_w_kernel(const float* __restrict__ w0, const float* __restrict__ w1,
                              const float* __restrict__ w2, const float* __restrict__ w3,
                              float* __restrict__ Wp) {
    int t = blockIdx.x * 256 + threadIdx.x;
    if (t >= 4 * WELEM) return;
    int p  = t / WELEM;
    int r  = t % WELEM;
    int co = r / (CN * 9);
    int q  = r % (CN * 9);
    int ci = q / 9;
    int k  = q % 9;
    const float* w = (p == 0) ? w0 : (p == 1) ? w1 : (p == 2) ? w2 : w3;
    Wp[p * WELEM + (((co >> 1) * CN + ci) * 9 + k) * 2 + (co & 1)] = w[r];
}

// One directional pass, recurrence carried through dense front buffer FR
// (ping-pong by step parity), synchronized by per-(step,tile,batch) flags.
// Each thread owns 2 output channels (co0, co0+1) at one line position.
template<int SSTRIDE, int LSTRIDE, int SLEN, int LLEN, int NCOT, int NLT, bool REV>
__global__ void __launch_bounds__(256)
pass_kernel(float* __restrict__ T, const float* __restrict__ Wp,
            float* __restrict__ FR, int* __restrict__ CNT) {
    constexpr int LW  = 80;   // 64 + 8 halo each side (float4-aligned window)
    constexpr int NF4 = LW / 4;
    __shared__ float sP[CN * LW];   // 40 KB

    const int blk = blockIdx.x;
    const int b   = blk / (NCOT * NLT);
    const int rem = blk % (NCOT * NLT);
    const int cot = rem / NLT;
    const int lt  = rem % NLT;
    const size_t b_off  = (size_t)b * BSTRIDE;
    const int l_base = lt * 64;
    const int lane   = threadIdx.x & 63;
    const int wv     = __builtin_amdgcn_readfirstlane(threadIdx.x >> 6);
    const int co0    = cot * 8 + wv * 2;
    const float* wg  = Wp + (size_t)(co0 >> 1) * (CN * 18);  // wave-uniform
    const int lo = (lt > 0) ? lt - 1 : 0;
    const int hi = (lt < NLT - 1) ? lt + 1 : NLT - 1;

    for (int t = 1; t < SLEN; ++t) {
        const int s  = REV ? (SLEN - 1 - t) : t;
        const int sp = REV ? (s + 1) : (s - 1);
        const int l  = l_base + lane;

        // Prefetch the += input (previous pass's data, no sync needed).
        const size_t oidx = b_off + (size_t)co0 * PLANE
                          + (size_t)s * SSTRIDE + (size_t)l * LSTRIDE;
        const float xv0 = T[oidx];
        const float xv1 = T[oidx + PLANE];

        // Wait for the producers of our tile (+halo) at step t-1.
        if (t > 1) {
            if (threadIdx.x == 0) {
                for (int q = lo; q <= hi; ++q) {
                    int* c = &CNT[((t - 1) * NLT + q) * BN + b];
                    while (__hip_atomic_load(c, __ATOMIC_RELAXED,
                                             __HIP_MEMORY_SCOPE_AGENT) < NCOT)
                        __builtin_amdgcn_s_sleep(1);
                }
                __threadfence();   // acquire: invalidate stale L1/L2
            }
        }
        __syncthreads();

        // Stage previous line (all 128 ci, our 80-wide window) into LDS.
        if (t == 1) {
            const float* Tp = T + b_off + (size_t)sp * SSTRIDE;
            for (int idx = threadIdx.x; idx < CN * NF4; idx += 256) {
                int ci = idx / NF4, j4 = idx % NF4;
                int gl = l_base - 8 + j4 * 4;
                float v0 = 0.f, v1 = 0.f, v2 = 0.f, v3 = 0.f;
                if (gl + 0 >= 0 && gl + 0 < LLEN) v0 = Tp[(size_t)ci * PLANE + (size_t)(gl + 0) * LSTRIDE];
                if (gl + 1 >= 0 && gl + 1 < LLEN) v1 = Tp[(size_t)ci * PLANE + (size_t)(gl + 1) * LSTRIDE];
                if (gl + 2 >= 0 && gl + 2 < LLEN) v2 = Tp[(size_t)ci * PLANE + (size_t)(gl + 2) * LSTRIDE];
                if (gl + 3 >= 0 && gl + 3 < LLEN) v3 = Tp[(size_t)ci * PLANE + (size_t)(gl + 3) * LSTRIDE];
                *(float4*)&sP[ci * LW + j4 * 4] = make_float4(v0, v1, v2, v3);
            }
        } else {
            const float* src = FR + (size_t)(((t - 1) & 1) * BN + b) * CN * LLEN;
            for (int idx = threadIdx.x; idx < CN * NF4; idx += 256) {
                int ci = idx / NF4, j4 = idx % NF4;
                int gl = l_base - 8 + j4 * 4;
                float4 v = make_float4(0.f, 0.f, 0.f, 0.f);
                if (gl >= 0 && gl + 3 < LLEN)
                    v = *(const float4*)(src + (size_t)ci * LLEN + gl);
                *(float4*)&sP[ci * LW + j4 * 4] = v;
            }
        }
        __syncthreads();

        // conv: acc[co] = sum_ci sum_k w[co][ci][k] * prev[ci][l+k-4]
        float acc0 = 0.f, acc1 = 0.f;
        const float* pr = &sP[lane + 4];
#pragma unroll 2
        for (int ci = 0; ci < CN; ++ci) {
            const float* wr = wg + ci * 18;
            const float* pp = pr + ci * LW;
#pragma unroll
            for (int k = 0; k < 9; ++k) {
                const float pv = pp[k];
                acc0 = fmaf(wr[2 * k],     pv, acc0);
                acc1 = fmaf(wr[2 * k + 1], pv, acc1);
            }
        }
        const float o0 = xv0 + (acc0 > 0.f ? acc0 : 0.f);
        const float o1 = xv1 + (acc1 > 0.f ? acc1 : 0.f);

        // Publish the new line to the front buffer (contiguous), release flag.
        float* dst = FR + ((size_t)((t & 1) * BN + b) * CN + co0) * LLEN + l;
        dst[0]    = o0;
        dst[LLEN] = o1;
        __syncthreads();   // drains all threads' FR stores (vmcnt0 at barrier)
        if (threadIdx.x == 0) {
            __threadfence();   // release: make FR stores device-visible
            __hip_atomic_fetch_add(&CNT[(t * NLT + lt) * BN + b], 1,
                                   __ATOMIC_RELAXED, __HIP_MEMORY_SCOPE_AGENT);
        }

        // Background output write (not on the recurrence critical path).
        T[oidx]         = o0;
        T[oidx + PLANE] = o1;
    }
}

extern "C" void kernel_launch(void* const* d_in, const int* in_sizes, int n_in,
                              void* d_out, int out_size, void* d_ws, size_t ws_size,
                              hipStream_t stream) {
    const float* x  = (const float*)d_in[0];
    const float* wd = (const float*)d_in[1];
    const float* wu = (const float*)d_in[2];
    const float* wr = (const float*)d_in[3];
    const float* wl = (const float*)d_in[4];
    float* T = (float*)d_out;

    float* Wp = (float*)d_ws;                 // 4*147456 floats = 2.36 MB
    float* FR = Wp + 4 * WELEM;               // 2*8*128*256 floats = 2 MB
    int*  CNT = (int*)(FR + 2 * BN * CN * WN);// 4*4096 ints = 64 KB

    hipMemcpyAsync(T, x, (size_t)BN * CN * HN * WN * sizeof(float),
                   hipMemcpyDeviceToDevice, stream);
    pack_w_kernel<<<(4 * WELEM + 255) / 256, 256, 0, stream>>>(wd, wu, wr, wl, Wp);
    hipMemsetAsync(CNT, 0, 4 * 4096 * sizeof(int), stream);

    // H passes: scan h (stride WN), line = w contiguous. 512 blocks (2/CU).
    // W passes: scan w (stride 1), line = h (stride WN). 256 blocks (1/CU).
    {
        float* W = Wp; int* C = CNT;
        void* args[] = { &T, &W, &FR, &C };
        hipLaunchCooperativeKernel((const void*)pass_kernel<WN, 1, HN, WN, 16, 4, false>,
                                   dim3(BN * 16 * 4), dim3(256), args, 0, stream);
    }
    {
        float* W = Wp + WELEM; int* C = CNT + 4096;
        void* args[] = { &T, &W, &FR, &C };
        hipLaunchCooperativeKernel((const void*)pass_kernel<WN, 1, HN, WN, 16, 4, true>,
                                   dim3(BN * 16 * 4), dim3(256), args, 0, stream);
    }
    {
        float* W = Wp + 2 * WELEM; int* C = CNT + 2 * 4096;
        void* args[] = { &T, &W, &FR, &C };
        hipLaunchCooperativeKernel((const void*)pass_kernel<1, WN, WN, HN, 16, 2, false>,
                                   dim3(BN * 16 * 2), dim3(256), args, 0, stream);
    }
    {
        float* W = Wp + 3 * WELEM; int* C = CNT + 3 * 4096;
        void* args[] = { &T, &W, &FR, &C };
        hipLaunchCooperativeKernel((const void*)pass_kernel<1, WN, WN, HN, 16, 2, true>,
                                   dim3(BN * 16 * 2), dim3(256), args, 0, stream);
    }
}

// Round 3
// 17000.645 us; speedup vs baseline: 2.4945x; 2.3409x over previous
//
#include <hip/hip_runtime.h>

#define BN 8
#define CN 128
#define HN 128
#define WN 256
#define PLANE (HN*WN)        // 32768
#define BSTRIDE (CN*PLANE)   // 4194304
#define WELEM (CN*CN*9)      // 147456 floats per direction

// Pack w[co][ci][k] -> Wq[g][c4][k][i][j], g=co/4, j=co%4, c4=ci/4, i=ci%4.
// A wave owns co-quad g (wave-uniform) -> 16 contiguous floats per (c4,k)
// go down the scalar pipe.
__global__ void pack_w_kernel(const float* __restrict__ w0, const float* __restrict__ w1,
                              const float* __restrict__ w2, const float* __restrict__ w3,
                              float* __restrict__ Wq) {
    int t = blockIdx.x * 256 + threadIdx.x;
    if (t >= 4 * WELEM) return;
    int p  = t / WELEM;
    int r  = t % WELEM;
    int co = r / (CN * 9);
    int q  = r % (CN * 9);
    int ci = q / 9;
    int k  = q % 9;
    const float* w = (p == 0) ? w0 : (p == 1) ? w1 : (p == 2) ? w2 : w3;
    int g = co >> 2, j = co & 3, c4 = ci >> 2, i = ci & 3;
    Wq[p * WELEM + ((g * 32 + c4) * 9 + k) * 16 + i * 4 + j] = w[r];
}

// One directional pass. Recurrence state flows through FR (l-major lines,
// FR[parity][b][l][ci]) with fine-grained agent-scope atomics; per-(step,
// tile,batch,co-tile) flags; NO cache-wide fences anywhere.
template<int SSTRIDE, int LSTRIDE, int SLEN, int LLEN, int NLT, bool REV>
__global__ void __launch_bounds__(256)
pass_kernel(float* __restrict__ T, const float* __restrict__ Wq,
            float* __restrict__ FR, unsigned int* __restrict__ FLG) {
    constexpr int NCOT  = 8;     // co-tiles (16 co per block)
    constexpr int LW    = 80;    // 64-wide tile + 8 halo each side
    constexpr int PITCH = 132;   // 128 ci + 4 pad (breaks bank collision)
    __shared__ float sP[LW * PITCH];   // 41.25 KB

    const int blk = blockIdx.x;
    const int b   = blk / (NCOT * NLT);
    const int rem = blk % (NCOT * NLT);
    const int cot = rem / NLT;
    const int lt  = rem % NLT;
    const int lane = threadIdx.x & 63;
    const int wv   = __builtin_amdgcn_readfirstlane((int)threadIdx.x >> 6);
    const int co0  = cot * 16 + wv * 4;
    const float* wg = Wq + (size_t)(co0 >> 2) * (32 * 9 * 16);  // wave-uniform
    const int l_base = lt * 64;
    const int l      = l_base + lane;
    const size_t b_off = (size_t)b * BSTRIDE;
    const int lo = (lt > 0) ? lt - 1 : 0;
    const int hi = (lt < NLT - 1) ? lt + 1 : NLT - 1;
    const int nd = (hi - lo + 1) * NCOT;

    for (int t = 1; t < SLEN; ++t) {
        const int s  = REV ? (SLEN - 1 - t) : t;
        const int sp = REV ? (s + 1) : (s - 1);
        const size_t oidx = b_off + (size_t)co0 * PLANE
                          + (size_t)s * SSTRIDE + (size_t)l * LSTRIDE;

        // x prefetch (our own co's only -> no cross-block hazard); overlaps poll.
        float xv0 = T[oidx];
        float xv1 = T[oidx + PLANE];
        float xv2 = T[oidx + 2 * (size_t)PLANE];
        float xv3 = T[oidx + 3 * (size_t)PLANE];

        // ---- wait for producers of step t-1 (tiles lo..hi, all co-tiles)
        if (t > 1 && (int)threadIdx.x < nd) {
            int qt = lo + ((int)threadIdx.x >> 3);
            int cq = (int)threadIdx.x & 7;
            const unsigned int* f =
                &FLG[(((t - 1) * NLT + qt) * BN + b) * NCOT + cq];
            while (__hip_atomic_load(f, __ATOMIC_RELAXED,
                                     __HIP_MEMORY_SCOPE_AGENT) == 0u)
                __builtin_amdgcn_s_sleep(1);
        }
        __syncthreads();

        // ---- stage previous line into LDS (l-major, ci-interleaved)
        if (t == 1) {
            const float* Tp = T + b_off + (size_t)sp * SSTRIDE;
            for (int r = threadIdx.x; r < LW * CN; r += 256) {
                int rl = r >> 7;          // / CN
                int ci = r & (CN - 1);
                int gl = l_base - 8 + rl;
                float v = 0.f;
                if (gl >= 0 && gl < LLEN)
                    v = Tp[(size_t)ci * PLANE + (size_t)gl * LSTRIDE];
                sP[rl * PITCH + ci] = v;
            }
        } else {
            const float* src = FR + (size_t)(((t - 1) & 1) * BN + b) * (CN * LLEN);
            for (int r = threadIdx.x; r < LW * (CN / 4); r += 256) {
                int rl = r >> 5;          // / 32
                int c4 = r & 31;
                int gl = l_base - 8 + rl;
                unsigned long long u0 = 0ull, u1 = 0ull;
                if (gl >= 0 && gl < LLEN) {
                    const unsigned long long* p =
                        (const unsigned long long*)(src + (size_t)gl * CN + c4 * 4);
                    u0 = __hip_atomic_load(p,     __ATOMIC_RELAXED, __HIP_MEMORY_SCOPE_AGENT);
                    u1 = __hip_atomic_load(p + 1, __ATOMIC_RELAXED, __HIP_MEMORY_SCOPE_AGENT);
                }
                float4 v;
                *(unsigned long long*)&v.x = u0;
                *(unsigned long long*)&v.z = u1;
                *(float4*)&sP[rl * PITCH + c4 * 4] = v;
            }
        }
        __syncthreads();

        // ---- conv: 4 co per thread, 4 ci per ds_read_b128
        float a0 = 0.f, a1 = 0.f, a2 = 0.f, a3 = 0.f;
        for (int c4 = 0; c4 < 32; ++c4) {
            const float* wr  = wg + c4 * 144;
            const float* spb = &sP[(lane + 4) * PITCH + c4 * 4];
            float4 tap[9];
#pragma unroll
            for (int k = 0; k < 9; ++k)
                tap[k] = *(const float4*)(spb + k * PITCH);
#pragma unroll
            for (int k = 0; k < 9; ++k) {
                const float* wk = wr + k * 16;
                a0 = fmaf(wk[0],  tap[k].x, a0); a1 = fmaf(wk[1],  tap[k].x, a1);
                a2 = fmaf(wk[2],  tap[k].x, a2); a3 = fmaf(wk[3],  tap[k].x, a3);
                a0 = fmaf(wk[4],  tap[k].y, a0); a1 = fmaf(wk[5],  tap[k].y, a1);
                a2 = fmaf(wk[6],  tap[k].y, a2); a3 = fmaf(wk[7],  tap[k].y, a3);
                a0 = fmaf(wk[8],  tap[k].z, a0); a1 = fmaf(wk[9],  tap[k].z, a1);
                a2 = fmaf(wk[10], tap[k].z, a2); a3 = fmaf(wk[11], tap[k].z, a3);
                a0 = fmaf(wk[12], tap[k].w, a0); a1 = fmaf(wk[13], tap[k].w, a1);
                a2 = fmaf(wk[14], tap[k].w, a2); a3 = fmaf(wk[15], tap[k].w, a3);
            }
        }
        const float o0 = xv0 + (a0 > 0.f ? a0 : 0.f);
        const float o1 = xv1 + (a1 > 0.f ? a1 : 0.f);
        const float o2 = xv2 + (a2 > 0.f ? a2 : 0.f);
        const float o3 = xv3 + (a3 > 0.f ? a3 : 0.f);

        // ---- publish new line to FR (write-through atomics), then flag
        {
            float* dst = FR + ((size_t)((t & 1) * BN + b) * LLEN + l) * CN + co0;
            float2 p0 = make_float2(o0, o1), p1 = make_float2(o2, o3);
            __hip_atomic_store((unsigned long long*)dst,
                               *(unsigned long long*)&p0,
                               __ATOMIC_RELAXED, __HIP_MEMORY_SCOPE_AGENT);
            __hip_atomic_store((unsigned long long*)dst + 1,
                               *(unsigned long long*)&p1,
                               __ATOMIC_RELAXED, __HIP_MEMORY_SCOPE_AGENT);
        }
        __builtin_amdgcn_s_waitcnt(0);   // drain own write-through stores
        __syncthreads();                 // now ALL block stores are at coherence point
        if (threadIdx.x == 0) {
            __hip_atomic_store(&FLG[((t * NLT + lt) * BN + b) * NCOT + cot], 1u,
                               __ATOMIC_RELAXED, __HIP_MEMORY_SCOPE_AGENT);
        }

        // ---- background output write (off critical path; L2 absorbs strides)
        T[oidx]                       = o0;
        T[oidx + PLANE]               = o1;
        T[oidx + 2 * (size_t)PLANE]   = o2;
        T[oidx + 3 * (size_t)PLANE]   = o3;
    }
}

extern "C" void kernel_launch(void* const* d_in, const int* in_sizes, int n_in,
                              void* d_out, int out_size, void* d_ws, size_t ws_size,
                              hipStream_t stream) {
    const float* x  = (const float*)d_in[0];
    const float* wd = (const float*)d_in[1];
    const float* wu = (const float*)d_in[2];
    const float* wr = (const float*)d_in[3];
    const float* wl = (const float*)d_in[4];
    float* T = (float*)d_out;

    float* Wq = (float*)d_ws;                        // 2.36 MB
    float* FR = Wq + 4 * WELEM;                      // 2 MB
    unsigned int* FLG = (unsigned int*)(FR + 2 * BN * CN * WN);  // 1 MB

    hipMemcpyAsync(T, x, (size_t)BN * CN * HN * WN * sizeof(float),
                   hipMemcpyDeviceToDevice, stream);
    pack_w_kernel<<<(4 * WELEM + 255) / 256, 256, 0, stream>>>(wd, wu, wr, wl, Wq);
    hipMemsetAsync(FLG, 0, 4 * 65536 * sizeof(unsigned int), stream);

    // H passes: scan h (SSTRIDE=WN), line = w (contiguous), 256 blocks.
    {
        float* W = Wq; unsigned int* F = FLG;
        void* args[] = { &T, &W, &FR, &F };
        hipLaunchCooperativeKernel((const void*)pass_kernel<WN, 1, HN, WN, 4, false>,
                                   dim3(BN * 8 * 4), dim3(256), args, 0, stream);
    }
    {
        float* W = Wq + WELEM; unsigned int* F = FLG + 65536;
        void* args[] = { &T, &W, &FR, &F };
        hipLaunchCooperativeKernel((const void*)pass_kernel<WN, 1, HN, WN, 4, true>,
                                   dim3(BN * 8 * 4), dim3(256), args, 0, stream);
    }
    // W passes: scan w (SSTRIDE=1), line = h (stride WN), 128 blocks.
    {
        float* W = Wq + 2 * WELEM; unsigned int* F = FLG + 2 * 65536;
        void* args[] = { &T, &W, &FR, &F };
        hipLaunchCooperativeKernel((const void*)pass_kernel<1, WN, WN, HN, 2, false>,
                                   dim3(BN * 8 * 2), dim3(256), args, 0, stream);
    }
    {
        float* W = Wq + 3 * WELEM; unsigned int* F = FLG + 3 * 65536;
        void* args[] = { &T, &W, &FR, &F };
        hipLaunchCooperativeKernel((const void*)pass_kernel<1, WN, WN, HN, 2, true>,
                                   dim3(BN * 8 * 2), dim3(256), args, 0, stream);
    }
}